// Round 1
// baseline (864.830 us; speedup 1.0000x reference)
//
#include <hip/hip_runtime.h>
#include <hip/hip_bf16.h>
#include <cstdint>

// Problem constants
#define B_   8
#define L_   2048
#define E_   1024
#define H_   16
#define D_   64
#define M_   (B_ * L_)     // 16384 rows for the big GEMMs
#define EPS_ 1e-6f
#define SEG  4             // L-segments for partial KV accumulation
#define LSEG (L_ / SEG)    // 512

typedef __bf16 bf16;
typedef __bf16 bf16x8 __attribute__((ext_vector_type(8)));
typedef __bf16 bf16x4 __attribute__((ext_vector_type(4)));
typedef float  floatx4 __attribute__((ext_vector_type(4)));

// ---------------------------------------------------------------------------
// async global->LDS, 16B per lane (dest = wave-uniform base + lane*16)
// ---------------------------------------------------------------------------
__device__ inline void async_cp16(const void* g, void* l) {
  __builtin_amdgcn_global_load_lds(
      (__attribute__((address_space(1))) void*)const_cast<void*>(g),
      (__attribute__((address_space(3))) void*)l,
      16, 0, 0);
}

// ---------------------------------------------------------------------------
// K1: fp32 -> bf16 elementwise convert (query -> Xbf), 8 elems/thread
// ---------------------------------------------------------------------------
__global__ __launch_bounds__(256) void k_convert_x(const float* __restrict__ x,
                                                   bf16* __restrict__ o) {
  size_t i = ((size_t)blockIdx.x * 256 + threadIdx.x) * 8;
  floatx4 a = *(const floatx4*)(x + i);
  floatx4 b = *(const floatx4*)(x + i + 4);
  bf16x8 r;
  r[0] = (bf16)a[0]; r[1] = (bf16)a[1]; r[2] = (bf16)a[2]; r[3] = (bf16)a[3];
  r[4] = (bf16)b[0]; r[5] = (bf16)b[1]; r[6] = (bf16)b[2]; r[7] = (bf16)b[3];
  *(bf16x8*)(o + i) = r;
}

// ---------------------------------------------------------------------------
// K2: transpose 4 weight matrices (E x E fp32, (in,out)) -> bf16 (out,in)
//     so the GEMM B-operand is K-contiguous ("bt" layout).
// ---------------------------------------------------------------------------
struct TArgs { const float* src[4]; bf16* dst[4]; };

__global__ __launch_bounds__(256) void k_transpose_w(TArgs t) {
  __shared__ float tile[32][33];  // +1 pad: no bank conflicts on transpose read
  const float* src = t.src[blockIdx.z];
  bf16* dst = t.dst[blockIdx.z];
  int bx = blockIdx.x, by = blockIdx.y;
  int x = threadIdx.x, y = threadIdx.y;  // (32, 8)
#pragma unroll
  for (int i = 0; i < 4; i++) {
    int r = by * 32 + y + i * 8;
    tile[y + i * 8][x] = src[(size_t)r * E_ + bx * 32 + x];
  }
  __syncthreads();
#pragma unroll
  for (int i = 0; i < 4; i++) {
    int r = bx * 32 + y + i * 8;   // row of dst = col of src
    dst[(size_t)r * E_ + by * 32 + x] = (bf16)tile[x][y + i * 8];
  }
}

// ---------------------------------------------------------------------------
// K3/K7: bf16 MFMA GEMM, C = A(MxK) @ Bt(NxK)^T + bias, m97 "gemm_bt" shape:
//   128x128 block tile, BK=32, 256 threads = 4 waves (2x2), each wave 64x64
//   via 4x4 tiles of v_mfma_f32_16x16x32_bf16. Both operands staged with
//   global_load_lds width=16 (contiguous LDS, no padding -- required).
//   Fragment layouts (m89/m91/m92 verified):
//     A/B frag: lane holds row (lane&15), k = (lane>>4)*8 + j  -> ds_read_b128
//     C/D:      col = lane&15, row = (lane>>4)*4 + reg
// ---------------------------------------------------------------------------
struct GemmArgs {
  const bf16*  Bt[3];
  const float* bias[3];
  void*        C[3];
  int          obf[3];   // 1 = bf16 output, 0 = fp32 output
};

__global__ __launch_bounds__(256) void k_gemm_bt(const bf16* __restrict__ A,
                                                 GemmArgs g, int Kd, int Nd) {
  __shared__ __attribute__((aligned(16))) bf16 As[128 * 32];  // 8 KB
  __shared__ __attribute__((aligned(16))) bf16 Bs[128 * 32];  // 8 KB
  const int z = blockIdx.z;
  const bf16*  Bt   = g.Bt[z];
  const float* bias = g.bias[z];

  const int tid  = threadIdx.x;
  const int wid  = tid >> 6;
  const int lane = tid & 63;
  const int quad = lane >> 4;
  const int l15  = lane & 15;
  const int wm   = wid >> 1, wn = wid & 1;
  const int bm   = blockIdx.y, bn = blockIdx.x;

  // staging addresses: wave `wid` fills rows [wid*32, wid*32+32) of each tile
  // inst j covers 16 rows: lane -> row (lane>>2), 16B chunk (lane&3)
  const bf16* ga0 = A  + (size_t)(bm * 128 + wid * 32 + (lane >> 2)) * Kd + (lane & 3) * 8;
  const bf16* ga1 = ga0 + (size_t)16 * Kd;
  const bf16* gb0 = Bt + (size_t)(bn * 128 + wid * 32 + (lane >> 2)) * Kd + (lane & 3) * 8;
  const bf16* gb1 = gb0 + (size_t)16 * Kd;
  bf16* la = &As[wid * 1024];   // wave-uniform LDS base (bytes: wid*2048)
  bf16* lb = &Bs[wid * 1024];

  floatx4 acc[4][4] = {};

  for (int kk = 0; kk < Kd; kk += 32) {
    async_cp16(ga0, la);        async_cp16(ga1, la + 512);
    async_cp16(gb0, lb);        async_cp16(gb1, lb + 512);
    ga0 += 32; ga1 += 32; gb0 += 32; gb1 += 32;
    __syncthreads();            // drains vmcnt before barrier (m97 structure)

    bf16x8 af[4], bfm[4];
#pragma unroll
    for (int i = 0; i < 4; i++)
      af[i] = *(const bf16x8*)&As[(wm * 64 + i * 16 + l15) * 32 + quad * 8];
#pragma unroll
    for (int i = 0; i < 4; i++)
      bfm[i] = *(const bf16x8*)&Bs[(wn * 64 + i * 16 + l15) * 32 + quad * 8];
#pragma unroll
    for (int i = 0; i < 4; i++)
#pragma unroll
      for (int j = 0; j < 4; j++)
        acc[i][j] = __builtin_amdgcn_mfma_f32_16x16x32_bf16(af[i], bfm[j], acc[i][j], 0, 0, 0);
    __syncthreads();            // LDS reads done before next stage overwrites
  }

  const int colb = bn * 128 + wn * 64 + l15;
  const int rowb = bm * 128 + wm * 64 + quad * 4;
  if (g.obf[z]) {
    bf16* C = (bf16*)g.C[z];
#pragma unroll
    for (int i = 0; i < 4; i++)
#pragma unroll
      for (int j = 0; j < 4; j++) {
        int col = colb + j * 16;
        float bv = bias[col];
#pragma unroll
        for (int r = 0; r < 4; r++) {
          int row = rowb + i * 16 + r;
          C[(size_t)row * Nd + col] = (bf16)(acc[i][j][r] + bv);
        }
      }
  } else {
    float* C = (float*)g.C[z];
#pragma unroll
    for (int i = 0; i < 4; i++)
#pragma unroll
      for (int j = 0; j < 4; j++) {
        int col = colb + j * 16;
        float bv = bias[col];
#pragma unroll
        for (int r = 0; r < 4; r++) {
          int row = rowb + i * 16 + r;
          C[(size_t)row * Nd + col] = acc[i][j][r] + bv;
        }
      }
  }
}

// ---------------------------------------------------------------------------
// K4: fused k-softmax + complement + sin/cos features + partial KV & ksum.
//  One block per (bh, seg). kf4 feature order f = part*64 + d:
//    part 0: k*sin, 1: k*cos, 2: (1-k)*sin, 3: (1-k)*cos
//  Thread t owns feature row f=t of the 256x64 KV accumulator (64 VGPRs).
// ---------------------------------------------------------------------------
__global__ __launch_bounds__(256) void k_kv_partial(const float* __restrict__ Kf,
                                                    const bf16* __restrict__ Vb,
                                                    float* __restrict__ kvp,
                                                    float* __restrict__ ksp) {
  const int bh  = blockIdx.x;        // 0..127
  const int seg = blockIdx.y;        // 0..SEG-1
  const int b = bh >> 4, h = bh & 15;
  const int t = threadIdx.x;
  __shared__ __attribute__((aligned(16))) bf16  kf4s[64 * 256];  // 32 KB
  __shared__ __attribute__((aligned(16))) float vs[64 * 64];     // 16 KB

  float acc[64];
#pragma unroll
  for (int i = 0; i < 64; i++) acc[i] = 0.f;
  float ks = 0.f;

  const int row = t >> 2, sub = t & 3;  // 4 lanes per l-row in phase A

  for (int c = 0; c < LSEG / 64; c++) {
    const int l = seg * LSEG + c * 64 + row;
    // ---- phase A: softmax + features into LDS ----
    const float* kp = Kf + ((size_t)(b * L_ + l) * E_ + h * 64 + sub * 16);
    floatx4 xv[4];
#pragma unroll
    for (int i = 0; i < 4; i++) xv[i] = *(const floatx4*)(kp + i * 4);
    float mx = -1e30f;
#pragma unroll
    for (int i = 0; i < 4; i++)
#pragma unroll
      for (int j = 0; j < 4; j++) mx = fmaxf(mx, xv[i][j]);
    mx = fmaxf(mx, __shfl_xor(mx, 1));
    mx = fmaxf(mx, __shfl_xor(mx, 2));
    float ev[16]; float s = 0.f;
#pragma unroll
    for (int i = 0; i < 4; i++)
#pragma unroll
      for (int j = 0; j < 4; j++) { float e = __expf(xv[i][j] - mx); ev[i * 4 + j] = e; s += e; }
    s += __shfl_xor(s, 1);
    s += __shfl_xor(s, 2);
    const float inv = 1.f / s;
    const float ang = 1.57079632679f * (float)(l + 1) / (float)L_;
    const float sn = __sinf(ang), cs = __cosf(ang);
#pragma unroll
    for (int i = 0; i < 16; i++) {
      const float p = ev[i] * inv;
      const int d = sub * 16 + i;
      kf4s[row * 256 + d]       = (bf16)(p * sn);
      kf4s[row * 256 + 64 + d]  = (bf16)(p * cs);
      kf4s[row * 256 + 128 + d] = (bf16)((1.f - p) * sn);
      kf4s[row * 256 + 192 + d] = (bf16)((1.f - p) * cs);
    }
    // stage V row slice as fp32 (cvt once here, not per-FMA in phase B)
    const bf16* vp = Vb + ((size_t)(b * L_ + l) * E_ + h * 64 + sub * 16);
    bf16x8 v0 = *(const bf16x8*)vp;
    bf16x8 v1 = *(const bf16x8*)(vp + 8);
#pragma unroll
    for (int i = 0; i < 8; i++) vs[row * 64 + sub * 16 + i]     = (float)v0[i];
#pragma unroll
    for (int i = 0; i < 8; i++) vs[row * 64 + sub * 16 + 8 + i] = (float)v1[i];
    __syncthreads();

    // ---- phase B: rank-1 accumulate KV[f][*] += kf4[l][f] * v[l][*] ----
#pragma unroll 2
    for (int ll = 0; ll < 64; ll++) {
      const float af = (float)kf4s[ll * 256 + t];
      ks += af;
#pragma unroll
      for (int d4 = 0; d4 < 16; d4++) {
        floatx4 vv = *(const floatx4*)&vs[ll * 64 + d4 * 4];  // wave-uniform: broadcast
        acc[d4 * 4 + 0] += af * vv[0];
        acc[d4 * 4 + 1] += af * vv[1];
        acc[d4 * 4 + 2] += af * vv[2];
        acc[d4 * 4 + 3] += af * vv[3];
      }
    }
    __syncthreads();
  }

  const size_t base = ((size_t)(seg * 128 + bh) * 256 + t) * 64;
#pragma unroll
  for (int d4 = 0; d4 < 16; d4++) {
    floatx4 o; o[0] = acc[d4*4+0]; o[1] = acc[d4*4+1]; o[2] = acc[d4*4+2]; o[3] = acc[d4*4+3];
    *(floatx4*)&kvp[base + d4 * 4] = o;
  }
  ksp[(seg * 128 + bh) * 256 + t] = ks;
}

// ---------------------------------------------------------------------------
// K5: reduce SEG partials -> KVb (bf16, 128x256x64) and ksum (fp32, 128x256)
// ---------------------------------------------------------------------------
__global__ __launch_bounds__(256) void k_kv_reduce(const float* __restrict__ kvp,
                                                   const float* __restrict__ ksp,
                                                   bf16* __restrict__ KVb,
                                                   float* __restrict__ ksum) {
  const int bh = blockIdx.x;
  const int f  = threadIdx.x;
  const size_t o = ((size_t)bh * 256 + f) * 64;
#pragma unroll 4
  for (int d4 = 0; d4 < 16; d4++) {
    floatx4 s = {0.f, 0.f, 0.f, 0.f};
    for (int g = 0; g < SEG; g++)
      s += *(const floatx4*)&kvp[((size_t)(g * 128 + bh) * 256 + f) * 64 + d4 * 4];
    bf16x4 r; r[0] = (bf16)s[0]; r[1] = (bf16)s[1]; r[2] = (bf16)s[2]; r[3] = (bf16)s[3];
    *(bf16x4*)&KVb[o + d4 * 4] = r;
  }
  float ss = 0.f;
  for (int g = 0; g < SEG; g++) ss += ksp[(g * 128 + bh) * 256 + f];
  ksum[bh * 256 + f] = ss;
}

// ---------------------------------------------------------------------------
// K6: fused q-softmax + z + (z-scaled qf4) @ KV -> attn rows (l*B+b, E) bf16.
//  Block = (bh, 32 l-rows). LDS = qs4 fp32 32KB + KV bf16 32KB = 64KB exactly.
//  Writing attn in (l*B+b) row order makes the final reshape a no-op.
// ---------------------------------------------------------------------------
__global__ __launch_bounds__(256) void k_attn_out(const float* __restrict__ Qf,
                                                  const bf16* __restrict__ KVb,
                                                  const float* __restrict__ ksum,
                                                  bf16* __restrict__ attn) {
  const int lc = blockIdx.x;   // 0..63 (chunks of 32 rows)
  const int bh = blockIdx.y;
  const int b = bh >> 4, h = bh & 15;
  const int t = threadIdx.x;
  __shared__ __attribute__((aligned(16))) float qs4[32 * 256];  // 32 KB
  __shared__ __attribute__((aligned(16))) bf16  kvs[256 * 64];  // 32 KB

  // phase 0: KV -> LDS (row f = t)
  {
    const bf16* src = KVb + (size_t)bh * 256 * 64 + (size_t)t * 64;
    bf16* dst = &kvs[t * 64];
#pragma unroll
    for (int i = 0; i < 8; i++) *(bf16x8*)(dst + i * 8) = *(const bf16x8*)(src + i * 8);
  }

  // phase 1: softmax + z + scaled features (8 lanes per l-row)
  const int row = t >> 3, sub = t & 7;
  const int l = lc * 32 + row;
  const float* qp = Qf + ((size_t)(b * L_ + l) * E_ + h * 64 + sub * 8);
  floatx4 xv0 = *(const floatx4*)qp;
  floatx4 xv1 = *(const floatx4*)(qp + 4);
  float mx = -1e30f;
#pragma unroll
  for (int j = 0; j < 4; j++) { mx = fmaxf(mx, xv0[j]); mx = fmaxf(mx, xv1[j]); }
  mx = fmaxf(mx, __shfl_xor(mx, 1));
  mx = fmaxf(mx, __shfl_xor(mx, 2));
  mx = fmaxf(mx, __shfl_xor(mx, 4));
  float ev[8]; float s = 0.f;
#pragma unroll
  for (int j = 0; j < 4; j++) { ev[j]     = __expf(xv0[j] - mx); s += ev[j]; }
#pragma unroll
  for (int j = 0; j < 4; j++) { ev[4 + j] = __expf(xv1[j] - mx); s += ev[4 + j]; }
  s += __shfl_xor(s, 1); s += __shfl_xor(s, 2); s += __shfl_xor(s, 4);
  const float inv = 1.f / s;

  const float* kb = ksum + bh * 256;
  float s1 = 0.f, s2 = 0.f, s3 = 0.f, s4 = 0.f, t3 = 0.f, t4 = 0.f;
  float p[8];
#pragma unroll
  for (int i = 0; i < 8; i++) {
    const int d = sub * 8 + i;
    p[i] = ev[i] * inv;
    const float k1 = kb[d], k2 = kb[64 + d], k3 = kb[128 + d], k4 = kb[192 + d];
    s1 += p[i] * k1; s2 += p[i] * k2; s3 += p[i] * k3; s4 += p[i] * k4;
    t3 += k3; t4 += k4;
  }
  s1 += __shfl_xor(s1, 1); s1 += __shfl_xor(s1, 2); s1 += __shfl_xor(s1, 4);
  s2 += __shfl_xor(s2, 1); s2 += __shfl_xor(s2, 2); s2 += __shfl_xor(s2, 4);
  s3 += __shfl_xor(s3, 1); s3 += __shfl_xor(s3, 2); s3 += __shfl_xor(s3, 4);
  s4 += __shfl_xor(s4, 1); s4 += __shfl_xor(s4, 2); s4 += __shfl_xor(s4, 4);
  t3 += __shfl_xor(t3, 1); t3 += __shfl_xor(t3, 2); t3 += __shfl_xor(t3, 4);
  t4 += __shfl_xor(t4, 1); t4 += __shfl_xor(t4, 2); t4 += __shfl_xor(t4, 4);

  const float ang = 1.57079632679f * (float)(l + 1) / (float)L_;
  const float sn = __sinf(ang), cs = __cosf(ang);
  const float den1 = sn * s1 + cs * s2;
  const float den2 = sn * (t3 - s3) + cs * (t4 - s4);
  const float z1 = 1.f / fmaxf(den1, EPS_);
  const float z2 = 1.f / fmaxf(den2, EPS_);
#pragma unroll
  for (int i = 0; i < 8; i++) {
    const int d = sub * 8 + i;
    qs4[row * 256 + d]       = z1 * sn * p[i];
    qs4[row * 256 + 64 + d]  = z1 * cs * p[i];
    qs4[row * 256 + 128 + d] = z2 * sn * (1.f - p[i]);
    qs4[row * 256 + 192 + d] = z2 * cs * (1.f - p[i]);
  }
  __syncthreads();

  // phase 2: out[l][d] = sum_f qs4[l][f] * KV[f][d]; thread = 2 l's x 4 d's
  const int lg = t >> 4, dg = t & 15;
  const float* q0 = &qs4[(lg * 2) * 256];
  const float* q1 = &qs4[(lg * 2 + 1) * 256];
  floatx4 a0 = {0.f, 0.f, 0.f, 0.f}, a1 = {0.f, 0.f, 0.f, 0.f};
#pragma unroll 8
  for (int f = 0; f < 256; f++) {
    const float c0 = q0[f], c1 = q1[f];           // broadcast reads
    bf16x4 kq = *(const bf16x4*)&kvs[f * 64 + dg * 4];
    floatx4 kf; kf[0] = (float)kq[0]; kf[1] = (float)kq[1]; kf[2] = (float)kq[2]; kf[3] = (float)kq[3];
    a0 += c0 * kf;
    a1 += c1 * kf;
  }
  const int l0 = lc * 32 + lg * 2;
#pragma unroll
  for (int li = 0; li < 2; li++) {
    floatx4 a = li ? a1 : a0;
    bf16x4 r; r[0] = (bf16)a[0]; r[1] = (bf16)a[1]; r[2] = (bf16)a[2]; r[3] = (bf16)a[3];
    const size_t rowg = (size_t)(l0 + li) * B_ + b;   // (L,B,*) row order
    *(bf16x4*)&attn[rowg * E_ + h * 64 + dg * 4] = r;
  }
}

// ---------------------------------------------------------------------------
// Host-side launch. Workspace layout (bytes), ~248 MB total:
// ---------------------------------------------------------------------------
#define WS_XBF  ((size_t)0)           // 33,554,432  bf16 X            (dead after QKV gemm)
#define WS_WT   ((size_t)33554432)    //  8,388,608  bf16 W^T x4 (q,k,v,o)
#define WS_QF   ((size_t)41943040)    // 67,108,864  fp32 Q
#define WS_KF   ((size_t)109051904)   // 67,108,864  fp32 K
#define WS_VB   ((size_t)176160768)   // 33,554,432  bf16 V
#define WS_KVP  ((size_t)209715200)   // 33,554,432  fp32 KV partials
#define WS_KSP  ((size_t)243269632)   //    524,288  fp32 ksum partials
#define WS_KVB  ((size_t)243793920)   //  4,194,304  bf16 KV
#define WS_KSUM ((size_t)247988224)   //    131,072  fp32 ksum
#define WS_ATTN WS_XBF                // 33,554,432  bf16 attn (overlays dead Xbf)

extern "C" void kernel_launch(void* const* d_in, const int* in_sizes, int n_in,
                              void* d_out, int out_size, void* d_ws, size_t ws_size,
                              hipStream_t stream) {
  (void)in_sizes; (void)n_in; (void)out_size; (void)ws_size;
  const float* query = (const float*)d_in[0];
  const float* Wq = (const float*)d_in[1];
  const float* bq = (const float*)d_in[2];
  const float* Wk = (const float*)d_in[3];
  const float* bk = (const float*)d_in[4];
  const float* Wv = (const float*)d_in[5];
  const float* bv = (const float*)d_in[6];
  const float* Wo = (const float*)d_in[7];
  const float* bo = (const float*)d_in[8];

  char* ws = (char*)d_ws;
  bf16*  Xbf  = (bf16*)(ws + WS_XBF);
  bf16*  Wt   = (bf16*)(ws + WS_WT);      // 4 matrices of E*E, order q,k,v,o
  float* Qf   = (float*)(ws + WS_QF);
  float* Kf   = (float*)(ws + WS_KF);
  bf16*  Vb   = (bf16*)(ws + WS_VB);
  float* kvp  = (float*)(ws + WS_KVP);
  float* ksp  = (float*)(ws + WS_KSP);
  bf16*  KVb  = (bf16*)(ws + WS_KVB);
  float* ksum = (float*)(ws + WS_KSUM);
  bf16*  attnb = (bf16*)(ws + WS_ATTN);

  // 1) X -> bf16
  k_convert_x<<<(M_ * E_) / (256 * 8), 256, 0, stream>>>(query, Xbf);

  // 2) W^T -> bf16 (N,K) for all four weights
  TArgs ta;
  ta.src[0] = Wq; ta.src[1] = Wk; ta.src[2] = Wv; ta.src[3] = Wo;
  ta.dst[0] = Wt;                ta.dst[1] = Wt + (size_t)E_ * E_;
  ta.dst[2] = Wt + (size_t)2 * E_ * E_; ta.dst[3] = Wt + (size_t)3 * E_ * E_;
  k_transpose_w<<<dim3(32, 32, 4), dim3(32, 8), 0, stream>>>(ta);

  // 3) batched QKV GEMM (z = 0,1,2): Q,K fp32 out; V bf16 out
  GemmArgs gq;
  gq.Bt[0] = Wt;                       gq.bias[0] = bq; gq.C[0] = Qf; gq.obf[0] = 0;
  gq.Bt[1] = Wt + (size_t)E_ * E_;     gq.bias[1] = bk; gq.C[1] = Kf; gq.obf[1] = 0;
  gq.Bt[2] = Wt + (size_t)2 * E_ * E_; gq.bias[2] = bv; gq.C[2] = Vb; gq.obf[2] = 1;
  k_gemm_bt<<<dim3(E_ / 128, M_ / 128, 3), 256, 0, stream>>>(Xbf, gq, E_, E_);

  // 4) partial KV + ksum (k-softmax fused)
  k_kv_partial<<<dim3(128, SEG), 256, 0, stream>>>(Kf, Vb, kvp, ksp);

  // 5) reduce partials
  k_kv_reduce<<<128, 256, 0, stream>>>(kvp, ksp, KVb, ksum);

  // 6) q-softmax + z + attn (writes (l*B+b)-ordered rows)
  k_attn_out<<<dim3(L_ / 32, 128), 256, 0, stream>>>(Qf, KVb, ksum, attnb);

  // 7) final projection -> d_out (fp32); flat layout already matches reference
  GemmArgs go;
  go.Bt[0] = Wt + (size_t)3 * E_ * E_; go.bias[0] = bo; go.C[0] = d_out; go.obf[0] = 0;
  go.Bt[1] = go.Bt[0]; go.bias[1] = bo; go.C[1] = d_out; go.obf[1] = 0;
  go.Bt[2] = go.Bt[0]; go.bias[2] = bo; go.C[2] = d_out; go.obf[2] = 0;
  k_gemm_bt<<<dim3(E_ / 128, M_ / 128, 1), 256, 0, stream>>>(attnb, go, E_, E_);
}